// Round 16
// baseline (476.860 us; speedup 1.0000x reference)
//
#include <hip/hip_runtime.h>
#include <hip/hip_bf16.h>

typedef __hip_bfloat16 bf16;
typedef unsigned short u16;
typedef unsigned int u32;
typedef __attribute__((ext_vector_type(8))) unsigned short ushort8;
typedef __attribute__((ext_vector_type(4))) unsigned short us4;
typedef __attribute__((ext_vector_type(4))) unsigned int uint4_t;
typedef __attribute__((ext_vector_type(8))) short bf16x8;
typedef __attribute__((ext_vector_type(4))) short bf16x4;
typedef __attribute__((ext_vector_type(4))) float f32x4;
typedef __attribute__((ext_vector_type(2))) _Float16 half2_t;

#define PL 65536          // H*W
#define EPS_LN 1e-6f

#if __has_builtin(__builtin_amdgcn_fdot2)
#define USE_FDOT2 1
#else
#define USE_FDOT2 0
#endif

__device__ __forceinline__ float fast_tanh(float v){
  float e = __expf(2.f*v);
  return 1.f - 2.f/(e+1.f);
}
__device__ __forceinline__ u16 f2bf(float f){
  bf16 h = __float2bfloat16(f);
  return __builtin_bit_cast(u16, h);
}
__device__ __forceinline__ float bf2f(u16 v){
  u32 u = ((u32)v) << 16;
  return __builtin_bit_cast(float, u);
}
__device__ __forceinline__ u16 f2h(float f){
  _Float16 h = (_Float16)f;
  return __builtin_bit_cast(u16, h);
}
__device__ __forceinline__ float h2f(u16 v){
  _Float16 h = __builtin_bit_cast(_Float16, v);
  return (float)h;
}
__device__ __forceinline__ float dot2h(u32 wpair, u32 kpair, float acc){
#if USE_FDOT2
  return __builtin_amdgcn_fdot2(__builtin_bit_cast(half2_t, wpair),
                                __builtin_bit_cast(half2_t, kpair), acc, false);
#else
  float a0 = h2f((u16)(wpair & 0xffff)), a1 = h2f((u16)(wpair >> 16));
  float k0 = h2f((u16)(kpair & 0xffff)), k1 = h2f((u16)(kpair >> 16));
  return acc + a0*k0 + a1*k1;
#endif
}
__device__ __forceinline__ u32 alignhalf(u32 hi, u32 lo){
  return (lo >> 16) | (hi << 16);
}

// ---------- pack weights to bf16 with padding / reorder ----------
__global__ void convert_w(const float* __restrict__ wq, const float* __restrict__ wkv,
                          const float* __restrict__ win, const float* __restrict__ wout,
                          const float* __restrict__ wproj,
                          u16* __restrict__ Wq, u16* __restrict__ Wkv,
                          u16* __restrict__ Wp0, u16* __restrict__ Wp1,
                          u16* __restrict__ Wproj, u16* __restrict__ Wh){
  int stride = gridDim.x * 256;
  int gid = blockIdx.x * 256 + threadIdx.x;
  for (int i = gid; i < 64*64;  i += stride) Wq[i]  = f2bf(wq[i]);
  for (int i = gid; i < 128*64; i += stride) Wkv[i] = f2bf(wkv[i]);
  for (int i = gid; i < 176*64; i += stride) {
    int r = i >> 6, c = i & 63;
    // half0 rows: 0..84 -> win[r] (t1_j), 85..169 -> win[170+(r-85)] (t2_j)
    Wp0[i] = (r < 85) ? f2bf(win[r*64+c]) : ((r < 170) ? f2bf(win[(85+r)*64+c]) : 0);
    // half1 rows: 0..84 -> win[85+r], 85..169 -> win[255+(r-85)]
    Wp1[i] = (r < 85) ? f2bf(win[(85+r)*64+c]) : ((r < 170) ? f2bf(win[(170+r)*64+c]) : 0);
  }
  for (int i = gid; i < 64*64; i += stride) Wproj[i] = f2bf(wproj[i]);
  for (int i = gid; i < 64*192; i += stride) {
    int o = i / 192, c = i % 192;
    Wh[i] = (c < 170) ? f2bf(wout[o*170 + c]) : 0;
  }
}

// ---------- fused LN (64ch) + MFMA GEMM (CAB paths), bf16 out ----------
__global__ __launch_bounds__(256) void ln_gemm(
    const float* __restrict__ x, const float* __restrict__ lnw,
    const float* __restrict__ lnb, const u16* __restrict__ W,
    u16* __restrict__ out, int MT, int Mvalid) {
  int b  = blockIdx.y;
  int p0 = blockIdx.x * 256;
  int tid = threadIdx.x;
  int lane = tid & 63, wv = tid >> 6;
  __shared__ u16 shX[256][72];
  {
    const float* xb = x + ((size_t)b * 64) * PL + p0 + tid;
    float xn[64];
    float mu = 0.f;
    #pragma unroll
    for (int c = 0; c < 64; ++c) { xn[c] = xb[(size_t)c * PL]; mu += xn[c]; }
    mu *= (1.f/64.f);
    float var = 0.f;
    #pragma unroll
    for (int c = 0; c < 64; ++c) { float d = xn[c]-mu; var += d*d; }
    var *= (1.f/64.f);
    float inv = rsqrtf(var + EPS_LN);
    #pragma unroll
    for (int c8 = 0; c8 < 8; ++c8) {
      ushort8 pk;
      #pragma unroll
      for (int j = 0; j < 8; ++j)
        pk[j] = f2bf((xn[c8*8+j]-mu)*inv*lnw[c8*8+j] + lnb[c8*8+j]);
      *reinterpret_cast<ushort8*>(&shX[tid][c8*8]) = pk;
    }
  }
  __syncthreads();
  int col = lane & 15, kg = lane >> 4;
  int n0 = wv * 64;
  bf16x8 bfr[4][2];
  #pragma unroll
  for (int nt = 0; nt < 4; ++nt)
    #pragma unroll
    for (int kh = 0; kh < 2; ++kh)
      bfr[nt][kh] = *reinterpret_cast<const bf16x8*>(&shX[n0 + nt*16 + col][kh*32 + kg*8]);
  for (int mt = 0; mt < MT; ++mt) {
    bf16x8 a0 = *reinterpret_cast<const bf16x8*>(&W[(mt*16+col)*64      + kg*8]);
    bf16x8 a1 = *reinterpret_cast<const bf16x8*>(&W[(mt*16+col)*64 + 32 + kg*8]);
    #pragma unroll
    for (int nt = 0; nt < 4; ++nt) {
      f32x4 acc = {0.f,0.f,0.f,0.f};
      acc = __builtin_amdgcn_mfma_f32_16x16x32_bf16(a0, bfr[nt][0], acc, 0,0,0);
      acc = __builtin_amdgcn_mfma_f32_16x16x32_bf16(a1, bfr[nt][1], acc, 0,0,0);
      int mbase = mt*16 + kg*4;
      #pragma unroll
      for (int r = 0; r < 4; ++r) {
        int ch = mbase + r;
        if (ch < Mvalid)
          out[((size_t)b*Mvalid + ch)*PL + p0 + n0 + nt*16 + col] = f2bf(acc[r]);
      }
    }
  }
}

// ---------- GEMM from pixel-major bf16 xn (LN-free), f16 out; 128-px tiles ----------
__global__ __launch_bounds__(256) void gemm_pm(
    const u16* __restrict__ xn, const u16* __restrict__ W,
    u16* __restrict__ out, int MT, int Mvalid) {
  int b  = blockIdx.y;
  int p0 = blockIdx.x * 128;
  int tid = threadIdx.x;
  int lane = tid & 63, wv = tid >> 6;
  __shared__ u16 shX[128][72];
  const u16* src = xn + ((size_t)b * PL + p0) * 64;
  #pragma unroll
  for (int i = 0; i < 4; ++i) {
    int idx = tid + i*256;           // 0..1023
    int px = idx >> 3, c8 = (idx & 7) << 3;
    *reinterpret_cast<ushort8*>(&shX[px][c8]) =
        *reinterpret_cast<const ushort8*>(src + (size_t)px*64 + c8);
  }
  __syncthreads();
  int col = lane & 15, kg = lane >> 4;
  int n0 = wv * 32;
  bf16x8 bfr[2][2];
  #pragma unroll
  for (int nt = 0; nt < 2; ++nt)
    #pragma unroll
    for (int kh = 0; kh < 2; ++kh)
      bfr[nt][kh] = *reinterpret_cast<const bf16x8*>(&shX[n0 + nt*16 + col][kh*32 + kg*8]);
  for (int mt = 0; mt < MT; ++mt) {
    bf16x8 a0 = *reinterpret_cast<const bf16x8*>(&W[(mt*16+col)*64      + kg*8]);
    bf16x8 a1 = *reinterpret_cast<const bf16x8*>(&W[(mt*16+col)*64 + 32 + kg*8]);
    #pragma unroll
    for (int nt = 0; nt < 2; ++nt) {
      f32x4 acc = {0.f,0.f,0.f,0.f};
      acc = __builtin_amdgcn_mfma_f32_16x16x32_bf16(a0, bfr[nt][0], acc, 0,0,0);
      acc = __builtin_amdgcn_mfma_f32_16x16x32_bf16(a1, bfr[nt][1], acc, 0,0,0);
      int mbase = mt*16 + kg*4;
      #pragma unroll
      for (int r = 0; r < 4; ++r) {
        int ch = mbase + r;
        if (ch < Mvalid)
          out[((size_t)b*Mvalid + ch)*PL + p0 + n0 + nt*16 + col] = f2h(acc[r]);
      }
    }
  }
}

// ---------- vectorized depthwise 3x3, SAME zero pad: 8-row x 256-col tile ----------
// cb=1: output plane index = class*4 + b ([c][b] layout); cb=0: [b][c]
__global__ __launch_bounds__(256) void dwconv3v(
    const u16* __restrict__ in, const float* __restrict__ w9,
    u16* __restrict__ out, int C, int cb) {
  int plane = blockIdx.y;               // 0..B*C-1  ([b][c] in)
  int cch = plane % C;
  int bb  = plane / C;
  int y0 = blockIdx.x * 8;              // 32 tiles
  int tid = threadIdx.x;
  const u16* ip = in + (size_t)plane * PL;
  __shared__ u16 sh[10][272];           // rows y0-1..y0+8; image col g at LDS col g+8
  #pragma unroll
  for (int i = 0; i < 2; ++i) {
    int idx = tid + i*256;
    if (idx < 320) {
      int r = idx >> 5, seg = idx & 31;
      int gy = y0 - 1 + r;
      ushort8 v = {0,0,0,0,0,0,0,0};
      if (gy >= 0 && gy < 256)
        v = *reinterpret_cast<const ushort8*>(ip + gy*256 + seg*8);
      *reinterpret_cast<ushort8*>(&sh[r][8 + seg*8]) = v;
    }
  }
  if (tid < 10) { sh[tid][7] = 0; sh[tid][264] = 0; }
  __syncthreads();
  float wk[9];
  #pragma unroll
  for (int i=0;i<9;++i) wk[i] = w9[cch*9+i];
  int lr = tid >> 5, xs = (tid & 31) * 8;
  float row[3][10];
  #pragma unroll
  for (int i = 0; i < 3; ++i) {
    ushort8 m = *reinterpret_cast<const ushort8*>(&sh[lr+i][8+xs]);
    row[i][0] = bf2f(sh[lr+i][7+xs]);
    #pragma unroll
    for (int j=0;j<8;++j) row[i][1+j] = bf2f((u16)m[j]);
    row[i][9] = bf2f(sh[lr+i][16+xs]);
  }
  ushort8 o;
  #pragma unroll
  for (int j = 0; j < 8; ++j) {
    float a = 0.f;
    #pragma unroll
    for (int i=0;i<3;++i)
      #pragma unroll
      for (int k=0;k<3;++k) a += wk[i*3+k]*row[i][j+k];
    o[j] = f2bf(a);
  }
  int gy = y0 + lr;
  int oplane = cb ? (cch*4 + bb) : plane;
  *reinterpret_cast<ushort8*>(out + (size_t)oplane*PL + gy*256 + xs) = o;
}

// ---------- stage-1 reduction, 8 px/thread; q [b][64], k classes [c][b] ----------
__global__ __launch_bounds__(256) void attn_reduce1(
    const u16* __restrict__ q, const u16* __restrict__ kv,
    float* __restrict__ part) {
  int bh = blockIdx.y;                // b*8+h
  int b = bh >> 3, h = bh & 7;
  int s = blockIdx.x;                 // chunk of 2048 pixels (32 chunks)
  int t = threadIdx.x;
  int p = s*2048 + t*8;
  const u16* qb = q  + ((size_t)b*64 + h*8) * PL + p;
  const u16* kb = kv + ((size_t)(h*8)*4 + b) * PL + p;
  ushort8 vq[8], vk[8];
  #pragma unroll
  for (int c=0;c<8;++c) {
    vq[c] = *reinterpret_cast<const ushort8*>(qb + (size_t)c*PL);
    vk[c] = *reinterpret_cast<const ushort8*>(kb + (size_t)c*4*PL);
  }
  float acc[80];
  #pragma unroll
  for (int i=0;i<80;++i) acc[i]=0.f;
  #pragma unroll
  for (int e = 0; e < 8; ++e) {
    float qe[8], ke[8];
    #pragma unroll
    for (int c=0;c<8;++c) { qe[c]=bf2f((u16)vq[c][e]); ke[c]=bf2f((u16)vk[c][e]); }
    #pragma unroll
    for (int c=0;c<8;++c)
      #pragma unroll
      for (int d=0;d<8;++d) acc[c*8+d] += qe[c]*ke[d];
    #pragma unroll
    for (int c=0;c<8;++c) { acc[64+c] += qe[c]*qe[c]; acc[72+c] += ke[c]*ke[c]; }
  }
  __shared__ float lds[4][80];
  int lane = t & 63, wv = t >> 6;
  #pragma unroll
  for (int i=0;i<80;++i) {
    float v = acc[i];
    for (int off=32; off; off>>=1) v += __shfl_down(v, off);
    if (lane==0) lds[wv][i]=v;
  }
  __syncthreads();
  if (t < 80)
    part[((size_t)bh*32 + s)*80 + t] = lds[0][t]+lds[1][t]+lds[2][t]+lds[3][t];
}

// ---------- stage-2 reduce + l2norm-folded softmax, one kernel ----------
__global__ void attn_finish(const float* __restrict__ part, const float* __restrict__ temp,
                            float* __restrict__ attn) {
  int bh = blockIdx.x; int t = threadIdx.x;
  __shared__ float red[80];
  if (t < 80) {
    float v = 0.f;
    for (int s=0;s<32;++s) v += part[((size_t)bh*32+s)*80+t];
    red[t]=v;
  }
  __syncthreads();
  if (t < 8) {
    int c = t, h = bh & 7;
    float nq = fmaxf(sqrtf(red[64+c]), 1e-12f);
    float tm = temp[h];
    float a[8]; float m=-1e30f;
    #pragma unroll
    for (int d=0;d<8;++d){
      float nk = fmaxf(sqrtf(red[72+d]), 1e-12f);
      a[d] = red[c*8+d]/(nq*nk) * tm; m=fmaxf(m,a[d]);
    }
    float ss=0.f;
    #pragma unroll
    for (int d=0;d<8;++d){ a[d]=__expf(a[d]-m); ss+=a[d]; }
    float inv=1.f/ss;
    #pragma unroll
    for (int d=0;d<8;++d) attn[bh*64 + c*8 + d] = a[d]*inv;
  }
}

// ---------- fused PV + w_proj + residual + LN -> xmid (f32) and xn (bf16 pixel-major) ----------
__global__ __launch_bounds__(256) void attn_pv_proj(
    const u16* __restrict__ kv, const float* __restrict__ attnb,
    const u16* __restrict__ Wp, const float* __restrict__ x,
    const float* __restrict__ lnw, const float* __restrict__ lnb,
    float* __restrict__ out, u16* __restrict__ xnb) {
  int b  = blockIdx.y;
  int p0 = blockIdx.x * 256;
  int tid = threadIdx.x;
  int lane = tid & 63, wv = tid >> 6;
  __shared__ float at[512];
  __shared__ float sw[64], sb[64];
  __shared__ u16 shX[256][72];
  for (int i=tid; i<512; i+=256) at[i]=attnb[b*512+i];
  if (tid < 64) { sw[tid]=lnw[tid]; sb[tid]=lnb[tid]; }
  __syncthreads();
  {
    int pix = p0 + tid;
    const u16* vb = kv + ((size_t)(64*4) + b)*PL + pix;  // v = classes 64..127, [c][b]
    #pragma unroll
    for (int h=0;h<8;++h){
      float vv[8];
      #pragma unroll
      for (int d=0;d<8;++d) vv[d]=bf2f(vb[(size_t)((h*8+d)*4)*PL]);
      ushort8 pk;
      #pragma unroll
      for (int c=0;c<8;++c){
        float acc=0.f;
        #pragma unroll
        for (int d=0;d<8;++d) acc += at[h*64+c*8+d]*vv[d];
        pk[c] = f2bf(acc);
      }
      *reinterpret_cast<ushort8*>(&shX[tid][h*8]) = pk;
    }
  }
  __syncthreads();
  int col = lane & 15, kg = lane >> 4;
  int n0 = wv * 64;
  bf16x8 bfr[4][2];
  #pragma unroll
  for (int nt = 0; nt < 4; ++nt)
    #pragma unroll
    for (int kh = 0; kh < 2; ++kh)
      bfr[nt][kh] = *reinterpret_cast<const bf16x8*>(&shX[n0 + nt*16 + col][kh*32 + kg*8]);
  f32x4 acc[4][4];
  #pragma unroll
  for (int mt = 0; mt < 4; ++mt) {
    bf16x8 a0 = *reinterpret_cast<const bf16x8*>(&Wp[(mt*16+col)*64      + kg*8]);
    bf16x8 a1 = *reinterpret_cast<const bf16x8*>(&Wp[(mt*16+col)*64 + 32 + kg*8]);
    #pragma unroll
    for (int nt = 0; nt < 4; ++nt) {
      f32x4 a = {0.f,0.f,0.f,0.f};
      a = __builtin_amdgcn_mfma_f32_16x16x32_bf16(a0, bfr[nt][0], a, 0,0,0);
      a = __builtin_amdgcn_mfma_f32_16x16x32_bf16(a1, bfr[nt][1], a, 0,0,0);
      acc[mt][nt] = a;
    }
  }
  // residual store + per-pixel LN stats (each lane holds 16 of the 64 channels)
  float s1[4] = {0.f,0.f,0.f,0.f}, s2[4] = {0.f,0.f,0.f,0.f};
  #pragma unroll
  for (int mt = 0; mt < 4; ++mt)
    #pragma unroll
    for (int nt = 0; nt < 4; ++nt)
      #pragma unroll
      for (int r = 0; r < 4; ++r) {
        int o = mt*16 + kg*4 + r;
        size_t idx = ((size_t)(b*64 + o))*PL + p0 + n0 + nt*16 + col;
        float v = x[idx] + acc[mt][nt][r];
        out[idx] = v;
        acc[mt][nt][r] = v;
        s1[nt] += v; s2[nt] += v*v;
      }
  #pragma unroll
  for (int nt = 0; nt < 4; ++nt) {
    s1[nt] += __shfl_xor(s1[nt], 16); s1[nt] += __shfl_xor(s1[nt], 32);
    s2[nt] += __shfl_xor(s2[nt], 16); s2[nt] += __shfl_xor(s2[nt], 32);
  }
  #pragma unroll
  for (int nt = 0; nt < 4; ++nt) {
    float mu = s1[nt] * (1.f/64.f);
    float var = s2[nt] * (1.f/64.f) - mu*mu;
    float inv = rsqrtf(var + EPS_LN);
    int pix = p0 + n0 + nt*16 + col;
    u16* xp = xnb + ((size_t)b*PL + pix)*64 + kg*4;
    #pragma unroll
    for (int mt = 0; mt < 4; ++mt) {
      us4 pk4;
      #pragma unroll
      for (int r = 0; r < 4; ++r) {
        int ch = mt*16 + kg*4 + r;
        pk4[r] = f2bf((acc[mt][nt][r]-mu)*inv*sw[ch] + sb[ch]);
      }
      *reinterpret_cast<us4*>(xp + mt*16) = pk4;
    }
  }
}

// ---------- IEL gate v7: XCD-chunked swizzle + f16 LDS + fdot2; P in [c][b] ----------
// t: [b][170][PL] f16 (planes 0..84 = t1_j, 85..169 = t2_j for this half)
// P: [170][b][PL] bf16, this half writes channel planes hcbase..hcbase+84
__global__ __launch_bounds__(256) void iel_gate2(
    const u16* __restrict__ t, const float* __restrict__ wdw,
    const float* __restrict__ wdw1, const float* __restrict__ wdw2,
    u16* __restrict__ P, int hcbase) {
  // bijective XCD-contiguous swizzle: N = 32*340 = 10880, N/8 = 1360
  int orig = blockIdx.x + (int)(gridDim.x * blockIdx.y);
  int nb = (orig & 7) * 1360 + (orig >> 3);
  int pj = nb >> 5;                     // 0..339
  int bx = nb & 31;                     // 0..31
  int b = pj / 85, j = pj % 85;
  int hc = hcbase + j;
  int y0 = (bx >> 2) * 32;
  int x0 = (bx & 3) * 64;
  int tid = threadIdx.x;

  __shared__ u16 sT[2][36][80];
  __shared__ u16 sD[2][34][72];

  const u16* t1 = t + (size_t)(b*170 + j) * PL;
  const u16* t2 = t + (size_t)(b*170 + 85 + j) * PL;

  #pragma unroll
  for (int it = 0; it < 3; ++it) {
    int idx = tid + it*256;
    if (idx < 720) {
      int pl = idx / 360, rem = idx % 360;
      int r = rem / 10, ch = rem % 10;
      int gy = y0 + r - 2;
      int gxb = x0 - 8 + ch*8;
      ushort8 v = {0,0,0,0,0,0,0,0};
      if (gy >= 0 && gy < 256 && gxb >= 0 && gxb <= 248)
        v = *reinterpret_cast<const ushort8*>((pl ? t2 : t1) + gy*256 + gxb);
      *reinterpret_cast<ushort8*>(&sT[pl][r][ch*8]) = v;
    }
  }
  __syncthreads();

  #pragma unroll
  for (int it = 0; it < 3; ++it) {
    int idx = tid + it*256;
    if (idx < 612) {
      int pl = idx / 306, rem = idx % 306;
      int r = rem / 9, si = rem % 9;
      int gy = y0 + r - 1;
      const float* kp = wdw + (pl ? (170+hc) : hc)*9;
      u32 k01[3], k2z[3];
      #pragma unroll
      for (int i=0;i<3;++i){
        k01[i] = (u32)f2h(kp[i*3+0]) | ((u32)f2h(kp[i*3+1]) << 16);
        k2z[i] = (u32)f2h(kp[i*3+2]);
      }
      float a[8];
      #pragma unroll
      for (int jj=0;jj<8;++jj) a[jj]=0.f;
      #pragma unroll
      for (int i = 0; i < 3; ++i) {
        ushort8 A0 = *reinterpret_cast<const ushort8*>(&sT[pl][r+i][si*8]);
        ushort8 A1 = *reinterpret_cast<const ushort8*>(&sT[pl][r+i][si*8+8]);
        uint4_t wa = __builtin_bit_cast(uint4_t, A0);
        uint4_t wb = __builtin_bit_cast(uint4_t, A1);
        u32 R1=wa.y, R2=wa.z, R3=wa.w, R4=wb.x, R5=wb.y, R6=wb.z;
        u32 prs[10] = { alignhalf(R2,R1), R2, alignhalf(R3,R2), R3,
                        alignhalf(R4,R3), R4, alignhalf(R5,R4), R5,
                        alignhalf(R6,R5), R6 };
        #pragma unroll
        for (int jj = 0; jj < 8; ++jj)
          a[jj] = dot2h(prs[jj+2], k2z[i], dot2h(prs[jj], k01[i], a[jj]));
      }
      int gx0 = x0 + si*8 - 4;
      bool rowok = (gy >= 0 && gy < 256);
      ushort8 dv;
      #pragma unroll
      for (int jj = 0; jj < 8; ++jj) {
        int gx = gx0 + jj;
        bool ok = rowok && gx >= 0 && gx < 256;
        dv[jj] = ok ? f2h(a[jj]) : (u16)0;
      }
      *reinterpret_cast<ushort8*>(&sD[pl][r][si*8]) = dv;
    }
  }
  __syncthreads();

  int ry = tid >> 3, seg = tid & 7;
  float x1[8], x2[8];
  #pragma unroll
  for (int pl = 0; pl < 2; ++pl) {
    const float* kp = (pl ? wdw2 : wdw1) + hc*9;
    u32 k01[3], k2z[3];
    #pragma unroll
    for (int i=0;i<3;++i){
      k01[i] = (u32)f2h(kp[i*3+0]) | ((u32)f2h(kp[i*3+1]) << 16);
      k2z[i] = (u32)f2h(kp[i*3+2]);
    }
    float a[8];
    #pragma unroll
    for (int jj=0;jj<8;++jj) a[jj]=0.f;
    float dc[8];
    #pragma unroll
    for (int i = 0; i < 3; ++i) {
      ushort8 A0 = *reinterpret_cast<const ushort8*>(&sD[pl][ry+i][seg*8]);
      ushort8 A1 = *reinterpret_cast<const ushort8*>(&sD[pl][ry+i][seg*8+8]);
      uint4_t wa = __builtin_bit_cast(uint4_t, A0);
      uint4_t wb = __builtin_bit_cast(uint4_t, A1);
      u32 R1=wa.y, R2=wa.z, R3=wa.w, R4=wb.x, R5=wb.y, R6=wb.z;
      u32 prs[10] = { alignhalf(R2,R1), R2, alignhalf(R3,R2), R3,
                      alignhalf(R4,R3), R4, alignhalf(R5,R4), R5,
                      alignhalf(R6,R5), R6 };
      #pragma unroll
      for (int jj = 0; jj < 8; ++jj)
        a[jj] = dot2h(prs[jj+2], k2z[i], dot2h(prs[jj], k01[i], a[jj]));
      if (i == 1) {
        u32 cw[4] = { wa.z, wa.w, wb.x, wb.y };   // halves 4..11
        #pragma unroll
        for (int jj = 0; jj < 8; ++jj) {
          u32 wrd = cw[(jj+4)/2 - 2];
          u16 hv = (jj & 1) ? (u16)(wrd >> 16) : (u16)(wrd & 0xffff);
          dc[jj] = h2f(hv);
        }
      }
    }
    #pragma unroll
    for (int jj = 0; jj < 8; ++jj) {
      float g = fast_tanh(a[jj]) + dc[jj];
      if (pl) x2[jj] = g; else x1[jj] = g;
    }
  }
  ushort8 o;
  #pragma unroll
  for (int jj = 0; jj < 8; ++jj) o[jj] = f2bf(x1[jj]*x2[jj]);
  int gy = y0 + ry;
  *reinterpret_cast<ushort8*>(
      P + ((size_t)((hcbase + j)*4 + b))*PL + gy*256 + x0 + seg*8) = o;
}

// ---------- IEL out-GEMM v3: 128-px tiles, double-buffered LDS, reg prefetch ----------
// out[b][o][px] += Wh[o][:] . P[:][b][px], K=170 pad 192; P in [c][b]
__global__ __launch_bounds__(256) void iel_gemm(
    const u16* __restrict__ Wh, const u16* __restrict__ P,
    float* __restrict__ out) {
  int b  = blockIdx.y;
  int p0 = blockIdx.x * 128;
  int tid = threadIdx.x;
  int lane = tid & 63, wv = tid >> 6;
  int col = lane & 15, kg = lane >> 4;
  int n0 = wv * 32;
  __shared__ u16 shP[2][128][36];
  f32x4 acc[4][2];
  #pragma unroll
  for (int mt=0;mt<4;++mt)
    #pragma unroll
    for (int nt=0;nt<2;++nt) acc[mt][nt] = (f32x4){0.f,0.f,0.f,0.f};

  int ch2 = (tid & 15) * 2;     // 2 channels per thread within 32-chunk
  int q   = tid >> 4;           // 0..15 pixel-group of 8

  ushort8 v[2];
  #pragma unroll
  for (int cc = 0; cc < 2; ++cc)
    v[cc] = *reinterpret_cast<const ushort8*>(
                P + ((size_t)(ch2+cc)*4 + b)*PL + p0 + q*8);
  for (int c = 0; c < 6; ++c) {
    int buf = c & 1;
    #pragma unroll
    for (int e = 0; e < 8; ++e) {
      u32 w = (u32)(u16)v[0][e] | ((u32)(u16)v[1][e] << 16);
      *reinterpret_cast<u32*>(&shP[buf][q*8 + e][ch2]) = w;
    }
    // issue next chunk's loads before the barrier (latency hides under MFMA)
    ushort8 vn[2];
    if (c < 5) {
      #pragma unroll
      for (int cc = 0; cc < 2; ++cc) {
        int hcl = (c+1)*32 + ch2 + cc;
        if (hcl < 170)
          vn[cc] = *reinterpret_cast<const ushort8*>(
                      P + ((size_t)hcl*4 + b)*PL + p0 + q*8);
        else
          vn[cc] = (ushort8){0,0,0,0,0,0,0,0};
      }
    } else {
      #pragma unroll
      for (int cc = 0; cc < 2; ++cc) vn[cc] = (ushort8){0,0,0,0,0,0,0,0};
    }
    __syncthreads();            // buf written by all; other buf free (read 2 phases ago)
    #pragma unroll
    for (int nt = 0; nt < 2; ++nt) {
      int px = n0 + nt*16 + col;
      const bf16x4* pp = reinterpret_cast<const bf16x4*>(&shP[buf][px][kg*8]);
      bf16x4 plo = pp[0], phi = pp[1];
      bf16x8 bfrag;
      #pragma unroll
      for (int jj=0;jj<4;++jj){ bfrag[jj]=plo[jj]; bfrag[4+jj]=phi[jj]; }
      #pragma unroll
      for (int mt = 0; mt < 4; ++mt) {
        bf16x8 a = *reinterpret_cast<const bf16x8*>(&Wh[(mt*16+col)*192 + c*32 + kg*8]);
        acc[mt][nt] = __builtin_amdgcn_mfma_f32_16x16x32_bf16(a, bfrag, acc[mt][nt], 0,0,0);
      }
    }
    #pragma unroll
    for (int cc = 0; cc < 2; ++cc) v[cc] = vn[cc];
  }
  #pragma unroll
  for (int mt=0; mt<4; ++mt)
    #pragma unroll
    for (int nt=0; nt<2; ++nt)
      #pragma unroll
      for (int r=0; r<4; ++r){
        int o = mt*16 + kg*4 + r;
        size_t idx = ((size_t)(b*64 + o))*PL + p0 + n0 + nt*16 + col;
        out[idx] += acc[mt][nt][r];
      }
}

extern "C" void kernel_launch(void* const* d_in, const int* in_sizes, int n_in,
                              void* d_out, int out_size, void* d_ws, size_t ws_size,
                              hipStream_t stream) {
  const float* x      = (const float*)d_in[0];
  const float* y      = (const float*)d_in[1];
  const float* lnw    = (const float*)d_in[2];
  const float* lnb    = (const float*)d_in[3];
  const float* temp   = (const float*)d_in[4];
  const float* wq     = (const float*)d_in[5];
  const float* wq_dw  = (const float*)d_in[6];
  const float* wkv    = (const float*)d_in[7];
  const float* wkv_dw = (const float*)d_in[8];
  const float* wproj  = (const float*)d_in[9];
  const float* w_in   = (const float*)d_in[10];
  const float* w_dw   = (const float*)d_in[11];
  const float* w_dw1  = (const float*)d_in[12];
  const float* w_dw2  = (const float*)d_in[13];
  const float* w_out  = (const float*)d_in[14];

  // ---- arena: 128KB weight head + 178.26MB data = 178.4 MB peak (proven-safe) ----
  char* base = (char*)d_ws;
  u16* Wq_b    = (u16*)(base + 0);        //  8,192 B
  u16* Wkv_b   = (u16*)(base + 8192);     // 16,384 B
  u16* Wp0     = (u16*)(base + 24576);    // 22,528 B
  u16* Wp1     = (u16*)(base + 47104);    // 22,528 B
  u16* Wproj_b = (u16*)(base + 69632);    //  8,192 B
  u16* Wh      = (u16*)(base + 77824);    // 24,576 B (ends 102,400)
  char* A = base + 131072;                // 178,257,920 B data region

  // CAB phase
  u16*  kvpre = (u16*)A;                  // 67,108,864 B [b][128][PL]
  u16*  kvd   = (u16*)(A + 89128960);     // 67,108,864 B [c][b][PL] (ends 156,237,824)
  u16*  qpre  = (u16*)A;                  // 33,554,432 B (kvpre dead)
  u16*  qd    = (u16*)(A + 33554432);     // 33,554,432 B [b][64][PL]
  float* part = (float*)A;                // 327,680 B (qpre dead)
  float* attnb= (float*)(A + 1572864);
  // xn: pixel-major LN(xmid), 33.5 MB — borrows kvd k-class region / Pbuf lower half
  u16*  xnb   = (u16*)(A + 89128960);
  // IEL phase
  u16*  tbuf  = (u16*)A;                  // 89,128,960 B [b][170][PL] (f16)
  u16*  Pbuf  = (u16*)(A + 89128960);     // 89,128,960 B [170][b][PL] (bf16)
  float* xmid = (float*)d_out;

  convert_w<<<64, 256, 0, stream>>>(wq, wkv, w_in, w_out, wproj,
                                    Wq_b, Wkv_b, Wp0, Wp1, Wproj_b, Wh);

  // ---- CAB ----
  ln_gemm<<<dim3(256,4), 256, 0, stream>>>(y, lnw, lnb, Wkv_b, kvpre, 8, 128);
  dwconv3v<<<dim3(32,512), 256, 0, stream>>>(kvpre, wkv_dw, kvd, 128, 1);
  ln_gemm<<<dim3(256,4), 256, 0, stream>>>(x, lnw, lnb, Wq_b, qpre, 4, 64);
  dwconv3v<<<dim3(32,256), 256, 0, stream>>>(qpre, wq_dw, qd, 64, 0);
  attn_reduce1<<<dim3(32,32), 256, 0, stream>>>(qd, kvd, part);
  attn_finish<<<32, 128, 0, stream>>>(part, temp, attnb);
  attn_pv_proj<<<dim3(256,4), 256, 0, stream>>>(kvd, attnb, Wproj_b, x, lnw, lnb,
                                                xmid, xnb);

  // ---- IEL: upper half first (keeps xn alive for the second GEMM) ----
  gemm_pm<<<dim3(512,4), 256, 0, stream>>>(xnb, Wp1, tbuf, 11, 170);
  iel_gate2<<<dim3(32,340), 256, 0, stream>>>(tbuf, w_dw, w_dw1, w_dw2, Pbuf, 85);
  gemm_pm<<<dim3(512,4), 256, 0, stream>>>(xnb, Wp0, tbuf, 11, 170);
  iel_gate2<<<dim3(32,340), 256, 0, stream>>>(tbuf, w_dw, w_dw1, w_dw2, Pbuf, 0);
  iel_gemm<<<dim3(512,4), 256, 0, stream>>>(Wh, Pbuf, xmid);
}

// Round 17
// 444.049 us; speedup vs baseline: 1.0739x; 1.0739x over previous
//
#include <hip/hip_runtime.h>
#include <hip/hip_bf16.h>

typedef __hip_bfloat16 bf16;
typedef unsigned short u16;
typedef unsigned int u32;
typedef __attribute__((ext_vector_type(8))) unsigned short ushort8;
typedef __attribute__((ext_vector_type(4))) unsigned short us4;
typedef __attribute__((ext_vector_type(4))) unsigned int uint4_t;
typedef __attribute__((ext_vector_type(8))) short bf16x8;
typedef __attribute__((ext_vector_type(4))) short bf16x4;
typedef __attribute__((ext_vector_type(4))) float f32x4;
typedef __attribute__((ext_vector_type(2))) _Float16 half2_t;

#define PL 65536          // H*W
#define EPS_LN 1e-6f

#if __has_builtin(__builtin_amdgcn_fdot2)
#define USE_FDOT2 1
#else
#define USE_FDOT2 0
#endif

__device__ __forceinline__ float fast_tanh(float v){
  float e = __expf(2.f*v);
  return 1.f - 2.f/(e+1.f);
}
__device__ __forceinline__ u16 f2bf(float f){
  bf16 h = __float2bfloat16(f);
  return __builtin_bit_cast(u16, h);
}
__device__ __forceinline__ float bf2f(u16 v){
  u32 u = ((u32)v) << 16;
  return __builtin_bit_cast(float, u);
}
__device__ __forceinline__ u16 f2h(float f){
  _Float16 h = (_Float16)f;
  return __builtin_bit_cast(u16, h);
}
__device__ __forceinline__ float h2f(u16 v){
  _Float16 h = __builtin_bit_cast(_Float16, v);
  return (float)h;
}
__device__ __forceinline__ float dot2h(u32 wpair, u32 kpair, float acc){
#if USE_FDOT2
  return __builtin_amdgcn_fdot2(__builtin_bit_cast(half2_t, wpair),
                                __builtin_bit_cast(half2_t, kpair), acc, false);
#else
  float a0 = h2f((u16)(wpair & 0xffff)), a1 = h2f((u16)(wpair >> 16));
  float k0 = h2f((u16)(kpair & 0xffff)), k1 = h2f((u16)(kpair >> 16));
  return acc + a0*k0 + a1*k1;
#endif
}
__device__ __forceinline__ u32 alignhalf(u32 hi, u32 lo){
  return (lo >> 16) | (hi << 16);
}

// ---------- pack weights to bf16 with padding / reorder ----------
__global__ void convert_w(const float* __restrict__ wq, const float* __restrict__ wkv,
                          const float* __restrict__ win, const float* __restrict__ wout,
                          const float* __restrict__ wproj,
                          u16* __restrict__ Wq, u16* __restrict__ Wkv,
                          u16* __restrict__ Wp0, u16* __restrict__ Wp1,
                          u16* __restrict__ Wproj, u16* __restrict__ Wh){
  int stride = gridDim.x * 256;
  int gid = blockIdx.x * 256 + threadIdx.x;
  for (int i = gid; i < 64*64;  i += stride) Wq[i]  = f2bf(wq[i]);
  for (int i = gid; i < 128*64; i += stride) Wkv[i] = f2bf(wkv[i]);
  for (int i = gid; i < 176*64; i += stride) {
    int r = i >> 6, c = i & 63;
    // half0 rows: 0..84 -> win[r] (t1_j), 85..169 -> win[170+(r-85)] (t2_j)
    Wp0[i] = (r < 85) ? f2bf(win[r*64+c]) : ((r < 170) ? f2bf(win[(85+r)*64+c]) : 0);
    // half1 rows: 0..84 -> win[85+r], 85..169 -> win[255+(r-85)]
    Wp1[i] = (r < 85) ? f2bf(win[(85+r)*64+c]) : ((r < 170) ? f2bf(win[(170+r)*64+c]) : 0);
  }
  for (int i = gid; i < 64*64; i += stride) Wproj[i] = f2bf(wproj[i]);
  for (int i = gid; i < 64*192; i += stride) {
    int o = i / 192, c = i % 192;
    Wh[i] = (c < 170) ? f2bf(wout[o*170 + c]) : 0;
  }
}

// ---------- fused LN (64ch) + MFMA GEMM (CAB paths), bf16 out ----------
__global__ __launch_bounds__(256) void ln_gemm(
    const float* __restrict__ x, const float* __restrict__ lnw,
    const float* __restrict__ lnb, const u16* __restrict__ W,
    u16* __restrict__ out, int MT, int Mvalid) {
  int b  = blockIdx.y;
  int p0 = blockIdx.x * 256;
  int tid = threadIdx.x;
  int lane = tid & 63, wv = tid >> 6;
  __shared__ u16 shX[256][72];
  {
    const float* xb = x + ((size_t)b * 64) * PL + p0 + tid;
    float xn[64];
    float mu = 0.f;
    #pragma unroll
    for (int c = 0; c < 64; ++c) { xn[c] = xb[(size_t)c * PL]; mu += xn[c]; }
    mu *= (1.f/64.f);
    float var = 0.f;
    #pragma unroll
    for (int c = 0; c < 64; ++c) { float d = xn[c]-mu; var += d*d; }
    var *= (1.f/64.f);
    float inv = rsqrtf(var + EPS_LN);
    #pragma unroll
    for (int c8 = 0; c8 < 8; ++c8) {
      ushort8 pk;
      #pragma unroll
      for (int j = 0; j < 8; ++j)
        pk[j] = f2bf((xn[c8*8+j]-mu)*inv*lnw[c8*8+j] + lnb[c8*8+j]);
      *reinterpret_cast<ushort8*>(&shX[tid][c8*8]) = pk;
    }
  }
  __syncthreads();
  int col = lane & 15, kg = lane >> 4;
  int n0 = wv * 64;
  bf16x8 bfr[4][2];
  #pragma unroll
  for (int nt = 0; nt < 4; ++nt)
    #pragma unroll
    for (int kh = 0; kh < 2; ++kh)
      bfr[nt][kh] = *reinterpret_cast<const bf16x8*>(&shX[n0 + nt*16 + col][kh*32 + kg*8]);
  for (int mt = 0; mt < MT; ++mt) {
    bf16x8 a0 = *reinterpret_cast<const bf16x8*>(&W[(mt*16+col)*64      + kg*8]);
    bf16x8 a1 = *reinterpret_cast<const bf16x8*>(&W[(mt*16+col)*64 + 32 + kg*8]);
    #pragma unroll
    for (int nt = 0; nt < 4; ++nt) {
      f32x4 acc = {0.f,0.f,0.f,0.f};
      acc = __builtin_amdgcn_mfma_f32_16x16x32_bf16(a0, bfr[nt][0], acc, 0,0,0);
      acc = __builtin_amdgcn_mfma_f32_16x16x32_bf16(a1, bfr[nt][1], acc, 0,0,0);
      int mbase = mt*16 + kg*4;
      #pragma unroll
      for (int r = 0; r < 4; ++r) {
        int ch = mbase + r;
        if (ch < Mvalid)
          out[((size_t)b*Mvalid + ch)*PL + p0 + n0 + nt*16 + col] = f2bf(acc[r]);
      }
    }
  }
}

// ---------- GEMM from pixel-major bf16 xn (LN-free), f16 out; 256-px tiles ----------
__global__ __launch_bounds__(256) void gemm_pm(
    const u16* __restrict__ xn, const u16* __restrict__ W,
    u16* __restrict__ out, int MT, int Mvalid) {
  int b  = blockIdx.y;
  int p0 = blockIdx.x * 256;
  int tid = threadIdx.x;
  int lane = tid & 63, wv = tid >> 6;
  __shared__ u16 shX[256][72];
  const u16* src = xn + ((size_t)b * PL + p0) * 64;
  #pragma unroll
  for (int c8 = 0; c8 < 8; ++c8)
    *reinterpret_cast<ushort8*>(&shX[tid][c8*8]) =
        *reinterpret_cast<const ushort8*>(src + (size_t)tid*64 + c8*8);
  __syncthreads();
  int col = lane & 15, kg = lane >> 4;
  int n0 = wv * 64;
  bf16x8 bfr[4][2];
  #pragma unroll
  for (int nt = 0; nt < 4; ++nt)
    #pragma unroll
    for (int kh = 0; kh < 2; ++kh)
      bfr[nt][kh] = *reinterpret_cast<const bf16x8*>(&shX[n0 + nt*16 + col][kh*32 + kg*8]);
  for (int mt = 0; mt < MT; ++mt) {
    bf16x8 a0 = *reinterpret_cast<const bf16x8*>(&W[(mt*16+col)*64      + kg*8]);
    bf16x8 a1 = *reinterpret_cast<const bf16x8*>(&W[(mt*16+col)*64 + 32 + kg*8]);
    #pragma unroll
    for (int nt = 0; nt < 4; ++nt) {
      f32x4 acc = {0.f,0.f,0.f,0.f};
      acc = __builtin_amdgcn_mfma_f32_16x16x32_bf16(a0, bfr[nt][0], acc, 0,0,0);
      acc = __builtin_amdgcn_mfma_f32_16x16x32_bf16(a1, bfr[nt][1], acc, 0,0,0);
      int mbase = mt*16 + kg*4;
      #pragma unroll
      for (int r = 0; r < 4; ++r) {
        int ch = mbase + r;
        if (ch < Mvalid)
          out[((size_t)b*Mvalid + ch)*PL + p0 + n0 + nt*16 + col] = f2h(acc[r]);
      }
    }
  }
}

// ---------- vectorized depthwise 3x3, SAME zero pad: 8-row x 256-col tile ----------
// cb=1: output plane index = class*4 + b ([c][b] layout); cb=0: [b][c]
__global__ __launch_bounds__(256) void dwconv3v(
    const u16* __restrict__ in, const float* __restrict__ w9,
    u16* __restrict__ out, int C, int cb) {
  int plane = blockIdx.y;               // 0..B*C-1  ([b][c] in)
  int cch = plane % C;
  int bb  = plane / C;
  int y0 = blockIdx.x * 8;              // 32 tiles
  int tid = threadIdx.x;
  const u16* ip = in + (size_t)plane * PL;
  __shared__ u16 sh[10][272];           // rows y0-1..y0+8; image col g at LDS col g+8
  #pragma unroll
  for (int i = 0; i < 2; ++i) {
    int idx = tid + i*256;
    if (idx < 320) {
      int r = idx >> 5, seg = idx & 31;
      int gy = y0 - 1 + r;
      ushort8 v = {0,0,0,0,0,0,0,0};
      if (gy >= 0 && gy < 256)
        v = *reinterpret_cast<const ushort8*>(ip + gy*256 + seg*8);
      *reinterpret_cast<ushort8*>(&sh[r][8 + seg*8]) = v;
    }
  }
  if (tid < 10) { sh[tid][7] = 0; sh[tid][264] = 0; }
  __syncthreads();
  float wk[9];
  #pragma unroll
  for (int i=0;i<9;++i) wk[i] = w9[cch*9+i];
  int lr = tid >> 5, xs = (tid & 31) * 8;
  float row[3][10];
  #pragma unroll
  for (int i = 0; i < 3; ++i) {
    ushort8 m = *reinterpret_cast<const ushort8*>(&sh[lr+i][8+xs]);
    row[i][0] = bf2f(sh[lr+i][7+xs]);
    #pragma unroll
    for (int j=0;j<8;++j) row[i][1+j] = bf2f((u16)m[j]);
    row[i][9] = bf2f(sh[lr+i][16+xs]);
  }
  ushort8 o;
  #pragma unroll
  for (int j = 0; j < 8; ++j) {
    float a = 0.f;
    #pragma unroll
    for (int i=0;i<3;++i)
      #pragma unroll
      for (int k=0;k<3;++k) a += wk[i*3+k]*row[i][j+k];
    o[j] = f2bf(a);
  }
  int gy = y0 + lr;
  int oplane = cb ? (cch*4 + bb) : plane;
  *reinterpret_cast<ushort8*>(out + (size_t)oplane*PL + gy*256 + xs) = o;
}

// ---------- stage-1 reduction, 8 px/thread; q [b][64], k classes [c][b] ----------
__global__ __launch_bounds__(256) void attn_reduce1(
    const u16* __restrict__ q, const u16* __restrict__ kv,
    float* __restrict__ part) {
  int bh = blockIdx.y;                // b*8+h
  int b = bh >> 3, h = bh & 7;
  int s = blockIdx.x;                 // chunk of 2048 pixels (32 chunks)
  int t = threadIdx.x;
  int p = s*2048 + t*8;
  const u16* qb = q  + ((size_t)b*64 + h*8) * PL + p;
  const u16* kb = kv + ((size_t)(h*8)*4 + b) * PL + p;
  ushort8 vq[8], vk[8];
  #pragma unroll
  for (int c=0;c<8;++c) {
    vq[c] = *reinterpret_cast<const ushort8*>(qb + (size_t)c*PL);
    vk[c] = *reinterpret_cast<const ushort8*>(kb + (size_t)c*4*PL);
  }
  float acc[80];
  #pragma unroll
  for (int i=0;i<80;++i) acc[i]=0.f;
  #pragma unroll
  for (int e = 0; e < 8; ++e) {
    float qe[8], ke[8];
    #pragma unroll
    for (int c=0;c<8;++c) { qe[c]=bf2f((u16)vq[c][e]); ke[c]=bf2f((u16)vk[c][e]); }
    #pragma unroll
    for (int c=0;c<8;++c)
      #pragma unroll
      for (int d=0;d<8;++d) acc[c*8+d] += qe[c]*ke[d];
    #pragma unroll
    for (int c=0;c<8;++c) { acc[64+c] += qe[c]*qe[c]; acc[72+c] += ke[c]*ke[c]; }
  }
  __shared__ float lds[4][80];
  int lane = t & 63, wv = t >> 6;
  #pragma unroll
  for (int i=0;i<80;++i) {
    float v = acc[i];
    for (int off=32; off; off>>=1) v += __shfl_down(v, off);
    if (lane==0) lds[wv][i]=v;
  }
  __syncthreads();
  if (t < 80)
    part[((size_t)bh*32 + s)*80 + t] = lds[0][t]+lds[1][t]+lds[2][t]+lds[3][t];
}

// ---------- stage-2 reduce + l2norm-folded softmax, one kernel ----------
__global__ void attn_finish(const float* __restrict__ part, const float* __restrict__ temp,
                            float* __restrict__ attn) {
  int bh = blockIdx.x; int t = threadIdx.x;
  __shared__ float red[80];
  if (t < 80) {
    float v = 0.f;
    for (int s=0;s<32;++s) v += part[((size_t)bh*32+s)*80+t];
    red[t]=v;
  }
  __syncthreads();
  if (t < 8) {
    int c = t, h = bh & 7;
    float nq = fmaxf(sqrtf(red[64+c]), 1e-12f);
    float tm = temp[h];
    float a[8]; float m=-1e30f;
    #pragma unroll
    for (int d=0;d<8;++d){
      float nk = fmaxf(sqrtf(red[72+d]), 1e-12f);
      a[d] = red[c*8+d]/(nq*nk) * tm; m=fmaxf(m,a[d]);
    }
    float ss=0.f;
    #pragma unroll
    for (int d=0;d<8;++d){ a[d]=__expf(a[d]-m); ss+=a[d]; }
    float inv=1.f/ss;
    #pragma unroll
    for (int d=0;d<8;++d) attn[bh*64 + c*8 + d] = a[d]*inv;
  }
}

// ---------- fused PV + w_proj + residual + LN -> xmid (f32) and xn (bf16 pixel-major) ----------
__global__ __launch_bounds__(256) void attn_pv_proj(
    const u16* __restrict__ kv, const float* __restrict__ attnb,
    const u16* __restrict__ Wp, const float* __restrict__ x,
    const float* __restrict__ lnw, const float* __restrict__ lnb,
    float* __restrict__ out, u16* __restrict__ xnb) {
  int b  = blockIdx.y;
  int p0 = blockIdx.x * 256;
  int tid = threadIdx.x;
  int lane = tid & 63, wv = tid >> 6;
  __shared__ float at[512];
  __shared__ float sw[64], sb[64];
  __shared__ u16 shX[256][72];
  for (int i=tid; i<512; i+=256) at[i]=attnb[b*512+i];
  if (tid < 64) { sw[tid]=lnw[tid]; sb[tid]=lnb[tid]; }
  __syncthreads();
  {
    int pix = p0 + tid;
    const u16* vb = kv + ((size_t)(64*4) + b)*PL + pix;  // v = classes 64..127, [c][b]
    #pragma unroll
    for (int h=0;h<8;++h){
      float vv[8];
      #pragma unroll
      for (int d=0;d<8;++d) vv[d]=bf2f(vb[(size_t)((h*8+d)*4)*PL]);
      ushort8 pk;
      #pragma unroll
      for (int c=0;c<8;++c){
        float acc=0.f;
        #pragma unroll
        for (int d=0;d<8;++d) acc += at[h*64+c*8+d]*vv[d];
        pk[c] = f2bf(acc);
      }
      *reinterpret_cast<ushort8*>(&shX[tid][h*8]) = pk;
    }
  }
  __syncthreads();
  int col = lane & 15, kg = lane >> 4;
  int n0 = wv * 64;
  bf16x8 bfr[4][2];
  #pragma unroll
  for (int nt = 0; nt < 4; ++nt)
    #pragma unroll
    for (int kh = 0; kh < 2; ++kh)
      bfr[nt][kh] = *reinterpret_cast<const bf16x8*>(&shX[n0 + nt*16 + col][kh*32 + kg*8]);
  f32x4 acc[4][4];
  #pragma unroll
  for (int mt = 0; mt < 4; ++mt) {
    bf16x8 a0 = *reinterpret_cast<const bf16x8*>(&Wp[(mt*16+col)*64      + kg*8]);
    bf16x8 a1 = *reinterpret_cast<const bf16x8*>(&Wp[(mt*16+col)*64 + 32 + kg*8]);
    #pragma unroll
    for (int nt = 0; nt < 4; ++nt) {
      f32x4 a = {0.f,0.f,0.f,0.f};
      a = __builtin_amdgcn_mfma_f32_16x16x32_bf16(a0, bfr[nt][0], a, 0,0,0);
      a = __builtin_amdgcn_mfma_f32_16x16x32_bf16(a1, bfr[nt][1], a, 0,0,0);
      acc[mt][nt] = a;
    }
  }
  // residual store + per-pixel LN stats (each lane holds 16 of the 64 channels)
  float s1[4] = {0.f,0.f,0.f,0.f}, s2[4] = {0.f,0.f,0.f,0.f};
  #pragma unroll
  for (int mt = 0; mt < 4; ++mt)
    #pragma unroll
    for (int nt = 0; nt < 4; ++nt)
      #pragma unroll
      for (int r = 0; r < 4; ++r) {
        int o = mt*16 + kg*4 + r;
        size_t idx = ((size_t)(b*64 + o))*PL + p0 + n0 + nt*16 + col;
        float v = x[idx] + acc[mt][nt][r];
        out[idx] = v;
        acc[mt][nt][r] = v;
        s1[nt] += v; s2[nt] += v*v;
      }
  #pragma unroll
  for (int nt = 0; nt < 4; ++nt) {
    s1[nt] += __shfl_xor(s1[nt], 16); s1[nt] += __shfl_xor(s1[nt], 32);
    s2[nt] += __shfl_xor(s2[nt], 16); s2[nt] += __shfl_xor(s2[nt], 32);
  }
  #pragma unroll
  for (int nt = 0; nt < 4; ++nt) {
    float mu = s1[nt] * (1.f/64.f);
    float var = s2[nt] * (1.f/64.f) - mu*mu;
    float inv = rsqrtf(var + EPS_LN);
    int pix = p0 + n0 + nt*16 + col;
    u16* xp = xnb + ((size_t)b*PL + pix)*64 + kg*4;
    #pragma unroll
    for (int mt = 0; mt < 4; ++mt) {
      us4 pk4;
      #pragma unroll
      for (int r = 0; r < 4; ++r) {
        int ch = mt*16 + kg*4 + r;
        pk4[r] = f2bf((acc[mt][nt][r]-mu)*inv*sw[ch] + sb[ch]);
      }
      *reinterpret_cast<us4*>(xp + mt*16) = pk4;
    }
  }
}

// ---------- IEL gate v7: XCD-chunked swizzle + f16 LDS + fdot2; P in [c][b] ----------
// t: [b][170][PL] f16 (planes 0..84 = t1_j, 85..169 = t2_j for this half)
// P: [170][b][PL] bf16, this half writes channel planes hcbase..hcbase+84
__global__ __launch_bounds__(256) void iel_gate2(
    const u16* __restrict__ t, const float* __restrict__ wdw,
    const float* __restrict__ wdw1, const float* __restrict__ wdw2,
    u16* __restrict__ P, int hcbase) {
  // bijective XCD-contiguous swizzle: N = 32*340 = 10880, N/8 = 1360
  int orig = blockIdx.x + (int)(gridDim.x * blockIdx.y);
  int nb = (orig & 7) * 1360 + (orig >> 3);
  int pj = nb >> 5;                     // 0..339
  int bx = nb & 31;                     // 0..31
  int b = pj / 85, j = pj % 85;
  int hc = hcbase + j;
  int y0 = (bx >> 2) * 32;
  int x0 = (bx & 3) * 64;
  int tid = threadIdx.x;

  __shared__ u16 sT[2][36][80];
  __shared__ u16 sD[2][34][72];

  const u16* t1 = t + (size_t)(b*170 + j) * PL;
  const u16* t2 = t + (size_t)(b*170 + 85 + j) * PL;

  #pragma unroll
  for (int it = 0; it < 3; ++it) {
    int idx = tid + it*256;
    if (idx < 720) {
      int pl = idx / 360, rem = idx % 360;
      int r = rem / 10, ch = rem % 10;
      int gy = y0 + r - 2;
      int gxb = x0 - 8 + ch*8;
      ushort8 v = {0,0,0,0,0,0,0,0};
      if (gy >= 0 && gy < 256 && gxb >= 0 && gxb <= 248)
        v = *reinterpret_cast<const ushort8*>((pl ? t2 : t1) + gy*256 + gxb);
      *reinterpret_cast<ushort8*>(&sT[pl][r][ch*8]) = v;
    }
  }
  __syncthreads();

  #pragma unroll
  for (int it = 0; it < 3; ++it) {
    int idx = tid + it*256;
    if (idx < 612) {
      int pl = idx / 306, rem = idx % 306;
      int r = rem / 9, si = rem % 9;
      int gy = y0 + r - 1;
      const float* kp = wdw + (pl ? (170+hc) : hc)*9;
      u32 k01[3], k2z[3];
      #pragma unroll
      for (int i=0;i<3;++i){
        k01[i] = (u32)f2h(kp[i*3+0]) | ((u32)f2h(kp[i*3+1]) << 16);
        k2z[i] = (u32)f2h(kp[i*3+2]);
      }
      float a[8];
      #pragma unroll
      for (int jj=0;jj<8;++jj) a[jj]=0.f;
      #pragma unroll
      for (int i = 0; i < 3; ++i) {
        ushort8 A0 = *reinterpret_cast<const ushort8*>(&sT[pl][r+i][si*8]);
        ushort8 A1 = *reinterpret_cast<const ushort8*>(&sT[pl][r+i][si*8+8]);
        uint4_t wa = __builtin_bit_cast(uint4_t, A0);
        uint4_t wb = __builtin_bit_cast(uint4_t, A1);
        u32 R1=wa.y, R2=wa.z, R3=wa.w, R4=wb.x, R5=wb.y, R6=wb.z;
        u32 prs[10] = { alignhalf(R2,R1), R2, alignhalf(R3,R2), R3,
                        alignhalf(R4,R3), R4, alignhalf(R5,R4), R5,
                        alignhalf(R6,R5), R6 };
        #pragma unroll
        for (int jj = 0; jj < 8; ++jj)
          a[jj] = dot2h(prs[jj+2], k2z[i], dot2h(prs[jj], k01[i], a[jj]));
      }
      int gx0 = x0 + si*8 - 4;
      bool rowok = (gy >= 0 && gy < 256);
      ushort8 dv;
      #pragma unroll
      for (int jj = 0; jj < 8; ++jj) {
        int gx = gx0 + jj;
        bool ok = rowok && gx >= 0 && gx < 256;
        dv[jj] = ok ? f2h(a[jj]) : (u16)0;
      }
      *reinterpret_cast<ushort8*>(&sD[pl][r][si*8]) = dv;
    }
  }
  __syncthreads();

  int ry = tid >> 3, seg = tid & 7;
  float x1[8], x2[8];
  #pragma unroll
  for (int pl = 0; pl < 2; ++pl) {
    const float* kp = (pl ? wdw2 : wdw1) + hc*9;
    u32 k01[3], k2z[3];
    #pragma unroll
    for (int i=0;i<3;++i){
      k01[i] = (u32)f2h(kp[i*3+0]) | ((u32)f2h(kp[i*3+1]) << 16);
      k2z[i] = (u32)f2h(kp[i*3+2]);
    }
    float a[8];
    #pragma unroll
    for (int jj=0;jj<8;++jj) a[jj]=0.f;
    float dc[8];
    #pragma unroll
    for (int i = 0; i < 3; ++i) {
      ushort8 A0 = *reinterpret_cast<const ushort8*>(&sD[pl][ry+i][seg*8]);
      ushort8 A1 = *reinterpret_cast<const ushort8*>(&sD[pl][ry+i][seg*8+8]);
      uint4_t wa = __builtin_bit_cast(uint4_t, A0);
      uint4_t wb = __builtin_bit_cast(uint4_t, A1);
      u32 R1=wa.y, R2=wa.z, R3=wa.w, R4=wb.x, R5=wb.y, R6=wb.z;
      u32 prs[10] = { alignhalf(R2,R1), R2, alignhalf(R3,R2), R3,
                      alignhalf(R4,R3), R4, alignhalf(R5,R4), R5,
                      alignhalf(R6,R5), R6 };
      #pragma unroll
      for (int jj = 0; jj < 8; ++jj)
        a[jj] = dot2h(prs[jj+2], k2z[i], dot2h(prs[jj], k01[i], a[jj]));
      if (i == 1) {
        u32 cw[4] = { wa.z, wa.w, wb.x, wb.y };   // halves 4..11
        #pragma unroll
        for (int jj = 0; jj < 8; ++jj) {
          u32 wrd = cw[(jj+4)/2 - 2];
          u16 hv = (jj & 1) ? (u16)(wrd >> 16) : (u16)(wrd & 0xffff);
          dc[jj] = h2f(hv);
        }
      }
    }
    #pragma unroll
    for (int jj = 0; jj < 8; ++jj) {
      float g = fast_tanh(a[jj]) + dc[jj];
      if (pl) x2[jj] = g; else x1[jj] = g;
    }
  }
  ushort8 o;
  #pragma unroll
  for (int jj = 0; jj < 8; ++jj) o[jj] = f2bf(x1[jj]*x2[jj]);
  int gy = y0 + ry;
  *reinterpret_cast<ushort8*>(
      P + ((size_t)((hcbase + j)*4 + b))*PL + gy*256 + x0 + seg*8) = o;
}

// ---------- IEL out-GEMM v2: register-prefetched pipeline, packed b64 LDS writes ----------
// out[b][o][px] += Wh[o][:] . P[:][b][px], K=170 pad 192; P in [c][b]
__global__ __launch_bounds__(256) void iel_gemm(
    const u16* __restrict__ Wh, const u16* __restrict__ P,
    float* __restrict__ out) {
  int b  = blockIdx.y;
  int p0 = blockIdx.x * 256;
  int tid = threadIdx.x;
  int lane = tid & 63, wv = tid >> 6;
  int col = lane & 15, kg = lane >> 4;
  int n0 = wv * 64;
  __shared__ u16 shP[256][36];
  f32x4 acc[4][4];
  #pragma unroll
  for (int mt=0;mt<4;++mt)
    #pragma unroll
    for (int nt=0;nt<4;++nt) acc[mt][nt] = (f32x4){0.f,0.f,0.f,0.f};

  int kk4 = (tid & 7) * 4;      // channel base within 32-chunk (thread owns 4 channels)
  int q   = tid >> 3;           // 0..31 pixel-group of 8

  ushort8 v[4];
  #pragma unroll
  for (int cc = 0; cc < 4; ++cc) {
    int hcl = kk4 + cc;         // chunk 0
    v[cc] = *reinterpret_cast<const ushort8*>(P + ((size_t)hcl*4 + b)*PL + p0 + q*8);
  }
  for (int c = 0; c < 6; ++c) {
    __syncthreads();            // previous chunk's MFMA reads complete
    #pragma unroll
    for (int e = 0; e < 8; ++e) {
      us4 pk;
      pk[0]=v[0][e]; pk[1]=v[1][e]; pk[2]=v[2][e]; pk[3]=v[3][e];
      *reinterpret_cast<us4*>(&shP[q*8 + e][kk4]) = pk;
    }
    // issue next chunk's loads before the barrier+MFMA (latency hides under them)
    ushort8 vn[4];
    if (c < 5) {
      #pragma unroll
      for (int cc = 0; cc < 4; ++cc) {
        int hcl = (c+1)*32 + kk4 + cc;
        if (hcl < 170)
          vn[cc] = *reinterpret_cast<const ushort8*>(
                      P + ((size_t)hcl*4 + b)*PL + p0 + q*8);
        else
          vn[cc] = (ushort8){0,0,0,0,0,0,0,0};
      }
    } else {
      #pragma unroll
      for (int cc = 0; cc < 4; ++cc) vn[cc] = (ushort8){0,0,0,0,0,0,0,0};
    }
    __syncthreads();
    #pragma unroll
    for (int nt = 0; nt < 4; ++nt) {
      int px = n0 + nt*16 + col;
      const bf16x4* pp = reinterpret_cast<const bf16x4*>(&shP[px][kg*8]);
      bf16x4 plo = pp[0], phi = pp[1];
      bf16x8 bfrag;
      #pragma unroll
      for (int jj=0;jj<4;++jj){ bfrag[jj]=plo[jj]; bfrag[4+jj]=phi[jj]; }
      #pragma unroll
      for (int mt = 0; mt < 4; ++mt) {
        bf16x8 a = *reinterpret_cast<const bf16x8*>(&Wh[(mt*16+col)*192 + c*32 + kg*8]);
        acc[mt][nt] = __builtin_amdgcn_mfma_f32_16x16x32_bf16(a, bfrag, acc[mt][nt], 0,0,0);
      }
    }
    #pragma unroll
    for (int cc = 0; cc < 4; ++cc) v[cc] = vn[cc];
  }
  #pragma unroll
  for (int mt=0; mt<4; ++mt)
    #pragma unroll
    for (int nt=0; nt<4; ++nt)
      #pragma unroll
      for (int r=0; r<4; ++r){
        int o = mt*16 + kg*4 + r;
        size_t idx = ((size_t)(b*64 + o))*PL + p0 + n0 + nt*16 + col;
        out[idx] += acc[mt][nt][r];
      }
}

extern "C" void kernel_launch(void* const* d_in, const int* in_sizes, int n_in,
                              void* d_out, int out_size, void* d_ws, size_t ws_size,
                              hipStream_t stream) {
  const float* x      = (const float*)d_in[0];
  const float* y      = (const float*)d_in[1];
  const float* lnw    = (const float*)d_in[2];
  const float* lnb    = (const float*)d_in[3];
  const float* temp   = (const float*)d_in[4];
  const float* wq     = (const float*)d_in[5];
  const float* wq_dw  = (const float*)d_in[6];
  const float* wkv    = (const float*)d_in[7];
  const float* wkv_dw = (const float*)d_in[8];
  const float* wproj  = (const float*)d_in[9];
  const float* w_in   = (const float*)d_in[10];
  const float* w_dw   = (const float*)d_in[11];
  const float* w_dw1  = (const float*)d_in[12];
  const float* w_dw2  = (const float*)d_in[13];
  const float* w_out  = (const float*)d_in[14];

  // ---- arena: 128KB weight head + 178.26MB data = 178.4 MB peak (proven-safe) ----
  char* base = (char*)d_ws;
  u16* Wq_b    = (u16*)(base + 0);        //  8,192 B
  u16* Wkv_b   = (u16*)(base + 8192);     // 16,384 B
  u16* Wp0     = (u16*)(base + 24576);    // 22,528 B
  u16* Wp1     = (u16*)(base + 47104);    // 22,528 B
  u16* Wproj_b = (u16*)(base + 69632);    //  8,192 B
  u16* Wh      = (u16*)(base + 77824);    // 24,576 B (ends 102,400)
  char* A = base + 131072;                // 178,257,920 B data region

  // CAB phase
  u16*  kvpre = (u16*)A;                  // 67,108,864 B [b][128][PL]
  u16*  kvd   = (u16*)(A + 89128960);     // 67,108,864 B [c][b][PL] (ends 156,237,824)
  u16*  qpre  = (u16*)A;                  // 33,554,432 B (kvpre dead)
  u16*  qd    = (u16*)(A + 33554432);     // 33,554,432 B [b][64][PL]
  float* part = (float*)A;                // 327,680 B (qpre dead)
  float* attnb= (float*)(A + 1572864);
  // xn: pixel-major LN(xmid), 33.5 MB — borrows kvd k-class region / Pbuf lower half
  u16*  xnb   = (u16*)(A + 89128960);
  // IEL phase
  u16*  tbuf  = (u16*)A;                  // 89,128,960 B [b][170][PL] (f16)
  u16*  Pbuf  = (u16*)(A + 89128960);     // 89,128,960 B [170][b][PL] (bf16)
  float* xmid = (float*)d_out;

  convert_w<<<64, 256, 0, stream>>>(wq, wkv, w_in, w_out, wproj,
                                    Wq_b, Wkv_b, Wp0, Wp1, Wproj_b, Wh);

  // ---- CAB ----
  ln_gemm<<<dim3(256,4), 256, 0, stream>>>(y, lnw, lnb, Wkv_b, kvpre, 8, 128);
  dwconv3v<<<dim3(32,512), 256, 0, stream>>>(kvpre, wkv_dw, kvd, 128, 1);
  ln_gemm<<<dim3(256,4), 256, 0, stream>>>(x, lnw, lnb, Wq_b, qpre, 4, 64);
  dwconv3v<<<dim3(32,256), 256, 0, stream>>>(qpre, wq_dw, qd, 64, 0);
  attn_reduce1<<<dim3(32,32), 256, 0, stream>>>(qd, kvd, part);
  attn_finish<<<32, 128, 0, stream>>>(part, temp, attnb);
  attn_pv_proj<<<dim3(256,4), 256, 0, stream>>>(kvd, attnb, Wproj_b, x, lnw, lnb,
                                                xmid, xnb);

  // ---- IEL: upper half first (keeps xn alive for the second GEMM) ----
  gemm_pm<<<dim3(256,4), 256, 0, stream>>>(xnb, Wp1, tbuf, 11, 170);
  iel_gate2<<<dim3(32,340), 256, 0, stream>>>(tbuf, w_dw, w_dw1, w_dw2, Pbuf, 85);
  gemm_pm<<<dim3(256,4), 256, 0, stream>>>(xnb, Wp0, tbuf, 11, 170);
  iel_gate2<<<dim3(32,340), 256, 0, stream>>>(tbuf, w_dw, w_dw1, w_dw2, Pbuf, 0);
  iel_gemm<<<dim3(256,4), 256, 0, stream>>>(Wh, Pbuf, xmid);
}